// Round 1
// baseline (2761.621 us; speedup 1.0000x reference)
//
#include <hip/hip_runtime.h>
#include <math.h>

// Problem constants (from reference)
constexpr int D  = 1024;
constexpr int H  = 16;
constexpr int HD = 64;   // head dim
constexpr int B  = 2;
constexpr int T  = 2048;
constexpr int M  = B * T; // 4096 rows

// ---------------------------------------------------------------------------
// GEMM: out[m,n] = sum_k X[m,k] * W[n,k]   (i.e. X @ W^T)
// OUT_MODE 0: plain [M, D] row-major
// OUT_MODE 1: head layout [B, H, T, HD]  (for Q/K/V)
// ---------------------------------------------------------------------------
template<int OUT_MODE>
__global__ __launch_bounds__(256)
void gemm_xwt(const float* __restrict__ X, const float* __restrict__ W,
              float* __restrict__ out) {
  constexpr int BM = 64, BN = 64, BK = 16;
  __shared__ float As[BM][BK + 1];
  __shared__ float Bs[BK][BN + 1];

  const int tid = threadIdx.x;
  const int tx = tid & 15;        // 0..15
  const int ty = tid >> 4;        // 0..15
  const int bx = blockIdx.x;      // N tile
  const int by = blockIdx.y;      // M tile
  const int row0 = by * BM;
  const int col0 = bx * BN;

  float acc[4][4] = {};

  for (int k0 = 0; k0 < D; k0 += BK) {
    // Load X tile (64x16), 4 contiguous floats per thread
    {
      int idx = tid * 4;
      int r = idx >> 4;
      int c = idx & 15;
      const float* src = X + (size_t)(row0 + r) * D + k0 + c;
      float4 v = *reinterpret_cast<const float4*>(src);
      As[r][c + 0] = v.x; As[r][c + 1] = v.y;
      As[r][c + 2] = v.z; As[r][c + 3] = v.w;
    }
    // Load W tile (rows n=64, cols k=16), store transposed into Bs[k][n]
    {
      int idx = tid * 4;
      int r = idx >> 4;
      int c = idx & 15;
      const float* src = W + (size_t)(col0 + r) * D + k0 + c;
      float4 v = *reinterpret_cast<const float4*>(src);
      Bs[c + 0][r] = v.x; Bs[c + 1][r] = v.y;
      Bs[c + 2][r] = v.z; Bs[c + 3][r] = v.w;
    }
    __syncthreads();

    #pragma unroll
    for (int k = 0; k < BK; ++k) {
      float a[4], b[4];
      #pragma unroll
      for (int i = 0; i < 4; ++i) a[i] = As[ty * 4 + i][k];
      #pragma unroll
      for (int j = 0; j < 4; ++j) b[j] = Bs[k][tx * 4 + j];
      #pragma unroll
      for (int i = 0; i < 4; ++i)
        #pragma unroll
        for (int j = 0; j < 4; ++j)
          acc[i][j] += a[i] * b[j];
    }
    __syncthreads();
  }

  #pragma unroll
  for (int i = 0; i < 4; ++i) {
    int m = row0 + ty * 4 + i;
    #pragma unroll
    for (int j = 0; j < 4; ++j) {
      int n = col0 + tx * 4 + j;
      if (OUT_MODE == 0) {
        out[(size_t)m * D + n] = acc[i][j];
      } else {
        int b  = m / T;
        int t  = m - b * T;
        int h  = n >> 6;       // n / HD
        int hd = n & 63;       // n % HD
        out[(((size_t)(b * H + h)) * T + t) * HD + hd] = acc[i][j];
      }
    }
  }
}

// ---------------------------------------------------------------------------
// RoPE in-place on [B*H, T, HD] buffer. Each thread handles pair (p, p+32).
// q'[p]    = q[p]*cos[t,p]    - q[p+32]*sin[t,p]
// q'[p+32] = q[p+32]*cos[t,p] + q[p]   *sin[t,p]   (cos/sin equal across halves)
// ---------------------------------------------------------------------------
__global__ __launch_bounds__(256)
void rope_kernel(float* __restrict__ buf, const float* __restrict__ cosT,
                 const float* __restrict__ sinT) {
  int idx = blockIdx.x * blockDim.x + threadIdx.x;  // B*H*T*32 threads
  int p  = idx & 31;
  int t  = (idx >> 5) & (T - 1);
  int bh = idx / (32 * T);
  size_t base = ((size_t)bh * T + t) * HD;
  float c = cosT[t * HD + p];
  float s = sinT[t * HD + p];
  float v1 = buf[base + p];
  float v2 = buf[base + p + 32];
  buf[base + p]      = v1 * c - v2 * s;
  buf[base + p + 32] = v2 * c + v1 * s;
}

// ---------------------------------------------------------------------------
// Flash-style causal attention.
// Q,K,V: [B*H, T, HD].  O: [B, T, D] (att output, pre-projection).
// Block: (qb, bh). 256 threads = 32 q-rows x 8 dim-groups (8 dims each).
// ---------------------------------------------------------------------------
__global__ __launch_bounds__(256)
void attn_kernel(const float* __restrict__ Q, const float* __restrict__ K,
                 const float* __restrict__ V, float* __restrict__ O) {
  __shared__ float Qs[32][HD];   // 8 KB
  __shared__ float Ks[64][HD];   // 16 KB
  __shared__ float Vs[64][HD];   // 16 KB
  __shared__ float Ps[32][64];   // 8 KB

  const int tid  = threadIdx.x;
  const int qr   = tid >> 3;   // 0..31  (query row in tile)
  const int g    = tid & 7;    // 0..7   (dim group / key group)
  const int qb   = blockIdx.x;
  const int bh   = blockIdx.y;
  const int qabs = qb * 32 + qr;
  const float scale = 0.125f;  // HD^-0.5 = 1/8

  const float* Qb = Q + (size_t)bh * T * HD;
  const float* Kb = K + (size_t)bh * T * HD;
  const float* Vb = V + (size_t)bh * T * HD;

  // Load Q tile: 32x64 floats, 8 per thread
  {
    int r  = tid >> 3;
    int c0 = (tid & 7) * 8;
    const float* src = Qb + (size_t)(qb * 32 + r) * HD + c0;
    *reinterpret_cast<float4*>(&Qs[r][c0])     = *reinterpret_cast<const float4*>(src);
    *reinterpret_cast<float4*>(&Qs[r][c0 + 4]) = *reinterpret_cast<const float4*>(src + 4);
  }

  float m_run = -INFINITY;
  float l_run = 0.f;
  float acc[8] = {};

  const int kb_max = (qb * 32 + 31) >> 6;   // inclusive
  for (int kb = 0; kb <= kb_max; ++kb) {
    const int j0 = kb * 64;
    // Load K,V tiles (64x64 each), 16 floats per thread per tile
    {
      int r  = tid >> 2;
      int c0 = (tid & 3) * 16;
      const float* ksrc = Kb + (size_t)(j0 + r) * HD + c0;
      const float* vsrc = Vb + (size_t)(j0 + r) * HD + c0;
      #pragma unroll
      for (int u = 0; u < 16; u += 4) {
        *reinterpret_cast<float4*>(&Ks[r][c0 + u]) = *reinterpret_cast<const float4*>(ksrc + u);
        *reinterpret_cast<float4*>(&Vs[r][c0 + u]) = *reinterpret_cast<const float4*>(vsrc + u);
      }
    }
    __syncthreads();

    // Scores for this thread's 8 keys
    float p[8];
    float smax = -INFINITY;
    #pragma unroll
    for (int kk = 0; kk < 8; ++kk) {
      int kj = g * 8 + kk;
      float s = 0.f;
      #pragma unroll
      for (int d = 0; d < HD; ++d) s += Qs[qr][d] * Ks[kj][d];
      s *= scale;
      if (j0 + kj > qabs) s = -INFINITY;
      p[kk] = s;
      smax = fmaxf(smax, s);
    }
    // Row max across the 8-thread group (same wave, aligned group)
    smax = fmaxf(smax, __shfl_xor(smax, 1));
    smax = fmaxf(smax, __shfl_xor(smax, 2));
    smax = fmaxf(smax, __shfl_xor(smax, 4));

    float m_new   = fmaxf(m_run, smax);       // finite: j0 <= qabs always
    float rescale = expf(m_run - m_new);      // expf(-inf)=0 on first block

    float psum = 0.f;
    #pragma unroll
    for (int kk = 0; kk < 8; ++kk) {
      float e = expf(p[kk] - m_new);          // masked -> 0
      p[kk] = e;
      psum += e;
    }
    psum += __shfl_xor(psum, 1);
    psum += __shfl_xor(psum, 2);
    psum += __shfl_xor(psum, 4);
    l_run = l_run * rescale + psum;
    m_run = m_new;

    #pragma unroll
    for (int i = 0; i < 8; ++i) acc[i] *= rescale;

    // Publish p to the row's 8-thread group via LDS (wave-internal, ordered)
    #pragma unroll
    for (int kk = 0; kk < 8; ++kk) Ps[qr][g * 8 + kk] = p[kk];

    // PV accumulate: thread owns dims [g*8, g*8+8)
    #pragma unroll
    for (int kj = 0; kj < 64; ++kj) {
      float pv = Ps[qr][kj];
      #pragma unroll
      for (int i = 0; i < 8; ++i) acc[i] += pv * Vs[kj][g * 8 + i];
    }
    __syncthreads();   // protect Ks/Vs before next load
  }

  float inv_l = 1.f / l_run;
  int b = bh / H;
  int h = bh - b * H;
  float* dst = O + ((size_t)(b * T + qabs)) * D + h * HD + g * 8;
  #pragma unroll
  for (int i = 0; i < 8; ++i) dst[i] = acc[i] * inv_l;
}

// ---------------------------------------------------------------------------
extern "C" void kernel_launch(void* const* d_in, const int* in_sizes, int n_in,
                              void* d_out, int out_size, void* d_ws, size_t ws_size,
                              hipStream_t stream) {
  const float* x    = (const float*)d_in[0];
  const float* cosT = (const float*)d_in[1];
  const float* sinT = (const float*)d_in[2];
  // d_in[3] = mask (int32) — causal, handled analytically
  const float* wq   = (const float*)d_in[4];
  const float* wk   = (const float*)d_in[5];
  const float* wv   = (const float*)d_in[6];
  const float* wo   = (const float*)d_in[7];

  float* out = (float*)d_out;

  const size_t seg = (size_t)B * H * T * HD;   // 4,194,304 floats = 16 MB
  float* q_ws   = (float*)d_ws;
  float* k_ws   = q_ws + seg;
  float* v_ws   = k_ws + seg;
  float* att_ws = v_ws + seg;

  dim3 ggrid(D / 64, M / 64);   // (16, 64)
  gemm_xwt<1><<<ggrid, 256, 0, stream>>>(x, wq, q_ws);
  gemm_xwt<1><<<ggrid, 256, 0, stream>>>(x, wk, k_ws);
  gemm_xwt<1><<<ggrid, 256, 0, stream>>>(x, wv, v_ws);

  int rope_threads = B * H * T * 32;
  rope_kernel<<<rope_threads / 256, 256, 0, stream>>>(q_ws, cosT, sinT);
  rope_kernel<<<rope_threads / 256, 256, 0, stream>>>(k_ws, cosT, sinT);

  dim3 agrid(T / 32, B * H);    // (64, 32)
  attn_kernel<<<agrid, 256, 0, stream>>>(q_ws, k_ws, v_ws, att_ws);

  gemm_xwt<0><<<ggrid, 256, 0, stream>>>(att_ws, wo, out);
}

// Round 2
// 201.299 us; speedup vs baseline: 13.7190x; 13.7190x over previous
//
#include <hip/hip_runtime.h>
#include <math.h>

// Problem constants
constexpr int D  = 1024;
constexpr int H  = 16;
constexpr int HD = 64;
constexpr int B  = 2;
constexpr int T  = 2048;
constexpr int M  = B * T;   // 4096

typedef float  f32x4  __attribute__((ext_vector_type(4)));
typedef __bf16 bf16x8 __attribute__((ext_vector_type(8)));
typedef __bf16 bf16x4 __attribute__((ext_vector_type(4)));

static __device__ inline f32x4 mfma16(bf16x8 a, bf16x8 b, f32x4 c) {
  return __builtin_amdgcn_mfma_f32_16x16x32_bf16(a, b, c, 0, 0, 0);
}

// ---------------------------------------------------------------------------
// fp32 -> bf16 convert (vectorized)
// ---------------------------------------------------------------------------
__global__ __launch_bounds__(256)
void cvt_f2b(const float* __restrict__ in, __bf16* __restrict__ out, int n) {
  int i = (blockIdx.x * 256 + threadIdx.x) * 4;
  if (i >= n) return;
  float4 v = *reinterpret_cast<const float4*>(in + i);
  bf16x4 o;
  o[0] = (__bf16)v.x; o[1] = (__bf16)v.y; o[2] = (__bf16)v.z; o[3] = (__bf16)v.w;
  *reinterpret_cast<bf16x4*>(out + i) = o;
}

// ---------------------------------------------------------------------------
// bf16 MFMA GEMM: C[m,n] = sum_k A[m,k] * Bw[n,k]   (A: [M,1024], Bw: [1024,1024])
// MODE 0: fp32 out [M,1024]
// MODE 1: bf16 out head layout [bh][t][hd]
// MODE 2: bf16 out head-transposed [bh][hd][t]
// 128x128 tile, BK=64, 256 threads (4 waves in 2x2), per-wave 64x64.
// ---------------------------------------------------------------------------
template<int MODE>
__global__ __launch_bounds__(256)
void gemm_bf16(const __bf16* __restrict__ A, const __bf16* __restrict__ Bw,
               void* __restrict__ outp) {
  constexpr int PAD = 8;
  __shared__ __bf16 As[128][64 + PAD];
  __shared__ __bf16 Bs[128][64 + PAD];

  const int tid  = threadIdx.x;
  const int lane = tid & 63;
  const int w    = tid >> 6;
  const int wm   = w >> 1, wn = w & 1;
  const int l15  = lane & 15, lg = lane >> 4;
  const int m0   = blockIdx.y * 128;
  const int n0   = blockIdx.x * 128;

  f32x4 acc[4][4];
  #pragma unroll
  for (int i = 0; i < 4; ++i)
    #pragma unroll
    for (int j = 0; j < 4; ++j)
      acc[i][j] = (f32x4){0.f, 0.f, 0.f, 0.f};

  const int srow = tid >> 1;           // 0..127
  const int scol = (tid & 1) * 32;

  for (int k0 = 0; k0 < 1024; k0 += 64) {
    const __bf16* ag = A  + (size_t)(m0 + srow) * 1024 + k0 + scol;
    const __bf16* bg = Bw + (size_t)(n0 + srow) * 1024 + k0 + scol;
    #pragma unroll
    for (int i = 0; i < 4; ++i) {
      *reinterpret_cast<bf16x8*>(&As[srow][scol + 8 * i]) =
          *reinterpret_cast<const bf16x8*>(ag + 8 * i);
      *reinterpret_cast<bf16x8*>(&Bs[srow][scol + 8 * i]) =
          *reinterpret_cast<const bf16x8*>(bg + 8 * i);
    }
    __syncthreads();

    #pragma unroll
    for (int ks = 0; ks < 2; ++ks) {
      bf16x8 af[4], bfr[4];
      #pragma unroll
      for (int mt = 0; mt < 4; ++mt)
        af[mt] = *reinterpret_cast<const bf16x8*>(&As[wm * 64 + mt * 16 + l15][ks * 32 + lg * 8]);
      #pragma unroll
      for (int nt = 0; nt < 4; ++nt)
        bfr[nt] = *reinterpret_cast<const bf16x8*>(&Bs[wn * 64 + nt * 16 + l15][ks * 32 + lg * 8]);
      #pragma unroll
      for (int mt = 0; mt < 4; ++mt)
        #pragma unroll
        for (int nt = 0; nt < 4; ++nt)
          acc[mt][nt] = mfma16(af[mt], bfr[nt], acc[mt][nt]);
    }
    __syncthreads();
  }

  // Epilogue. C layout per 16x16 tile: col = l15 (n), row = lg*4 + r (m).
  #pragma unroll
  for (int mt = 0; mt < 4; ++mt) {
    #pragma unroll
    for (int nt = 0; nt < 4; ++nt) {
      const int n  = n0 + wn * 64 + nt * 16 + l15;
      const int mb = m0 + wm * 64 + mt * 16 + lg * 4;
      #pragma unroll
      for (int r = 0; r < 4; ++r) {
        const int m = mb + r;
        float v = acc[mt][nt][r];
        if (MODE == 0) {
          ((float*)outp)[(size_t)m * 1024 + n] = v;
        } else {
          const int b  = m >> 11;        // m / T
          const int t  = m & 2047;
          const int h  = n >> 6;
          const int hd = n & 63;
          if (MODE == 1)
            ((__bf16*)outp)[(((size_t)(b * H + h)) * T + t) * HD + hd] = (__bf16)v;
          else
            ((__bf16*)outp)[(((size_t)(b * H + h)) * HD + hd) * T + t] = (__bf16)v;
        }
      }
    }
  }
}

// ---------------------------------------------------------------------------
// RoPE in-place on bf16 [bh][t][64]; thread handles 4 pairs (p..p+3, +32).
// ---------------------------------------------------------------------------
__global__ __launch_bounds__(256)
void rope_b(__bf16* __restrict__ buf, const float* __restrict__ cosT,
            const float* __restrict__ sinT) {
  int idx = blockIdx.x * 256 + threadIdx.x;     // B*H*T*8 threads
  int pg  = (idx & 7) * 4;                      // 0..28
  int t   = (idx >> 3) & (T - 1);
  int bh  = idx >> 14;                          // / (8*T)
  size_t base = ((size_t)bh * T + t) * HD;
  bf16x4 a = *reinterpret_cast<bf16x4*>(buf + base + pg);
  bf16x4 b = *reinterpret_cast<bf16x4*>(buf + base + pg + 32);
  float4 c = *reinterpret_cast<const float4*>(cosT + t * HD + pg);
  float4 s = *reinterpret_cast<const float4*>(sinT + t * HD + pg);
  float a0 = (float)a[0], a1 = (float)a[1], a2 = (float)a[2], a3 = (float)a[3];
  float b0 = (float)b[0], b1 = (float)b[1], b2 = (float)b[2], b3 = (float)b[3];
  bf16x4 ao, bo;
  ao[0] = (__bf16)(a0 * c.x - b0 * s.x); bo[0] = (__bf16)(b0 * c.x + a0 * s.x);
  ao[1] = (__bf16)(a1 * c.y - b1 * s.y); bo[1] = (__bf16)(b1 * c.y + a1 * s.y);
  ao[2] = (__bf16)(a2 * c.z - b2 * s.z); bo[2] = (__bf16)(b2 * c.z + a2 * s.z);
  ao[3] = (__bf16)(a3 * c.w - b3 * s.w); bo[3] = (__bf16)(b3 * c.w + a3 * s.w);
  *reinterpret_cast<bf16x4*>(buf + base + pg)      = ao;
  *reinterpret_cast<bf16x4*>(buf + base + pg + 32) = bo;
}

// ---------------------------------------------------------------------------
// MFMA flash attention (causal).
// Q,K: bf16 [bh][t][64] (rope'd). Vt: bf16 [bh][64][t]. Out: bf16 [M][1024].
// Block: 256 thr = 4 waves; q-tile 64 (16 rows/wave); kv-tile 64.
// Swapped QK^T: S^T = mfma(K, Q) -> lane holds 16 keys for q = lane&15.
// PV: O^T = mfma(V^T, P^T); state and O^T share the q = lane&15 mapping.
// ---------------------------------------------------------------------------
__global__ __launch_bounds__(256)
void attn_mfma(const __bf16* __restrict__ Q, const __bf16* __restrict__ K,
               const __bf16* __restrict__ Vt, __bf16* __restrict__ Ob) {
  __shared__ __bf16 Ks[64][72];      // K[key][hd]
  __shared__ __bf16 Vs[64][72];      // V^T[hd][key]
  __shared__ __bf16 Ps[4][16][72];   // per-wave P^T staging [q][key]

  const int tid  = threadIdx.x;
  const int lane = tid & 63;
  const int w    = tid >> 6;
  const int l15  = lane & 15, lg = lane >> 4;
  const int qb   = blockIdx.x;
  const int bh   = blockIdx.y;
  const int q_abs = qb * 64 + w * 16 + l15;

  const __bf16* Qb = Q  + (size_t)bh * T * HD;
  const __bf16* Kb = K  + (size_t)bh * T * HD;
  const __bf16* Vb = Vt + (size_t)bh * HD * T;

  bf16x8 qf[2];
  qf[0] = *reinterpret_cast<const bf16x8*>(Qb + (size_t)q_abs * HD + lg * 8);
  qf[1] = *reinterpret_cast<const bf16x8*>(Qb + (size_t)q_abs * HD + 32 + lg * 8);

  float m_run = -INFINITY, l_run = 0.f;
  f32x4 oacc[4];
  #pragma unroll
  for (int i = 0; i < 4; ++i) oacc[i] = (f32x4){0.f, 0.f, 0.f, 0.f};

  const int srow = tid >> 2;        // 0..63
  const int sc0  = (tid & 3) * 16;

  for (int kb = 0; kb <= qb; ++kb) {
    const int j0 = kb * 64;
    // Stage K tile [key][hd] and V^T tile [hd][key]
    {
      const __bf16* ks = Kb + (size_t)(j0 + srow) * HD + sc0;
      const __bf16* vs = Vb + (size_t)srow * T + j0 + sc0;
      *reinterpret_cast<bf16x8*>(&Ks[srow][sc0])     = *reinterpret_cast<const bf16x8*>(ks);
      *reinterpret_cast<bf16x8*>(&Ks[srow][sc0 + 8]) = *reinterpret_cast<const bf16x8*>(ks + 8);
      *reinterpret_cast<bf16x8*>(&Vs[srow][sc0])     = *reinterpret_cast<const bf16x8*>(vs);
      *reinterpret_cast<bf16x8*>(&Vs[srow][sc0 + 8]) = *reinterpret_cast<const bf16x8*>(vs + 8);
    }
    __syncthreads();

    // S^T = K . Q^T : 4 key-tiles x 2 k-steps
    f32x4 sa[4];
    #pragma unroll
    for (int kt = 0; kt < 4; ++kt) sa[kt] = (f32x4){0.f, 0.f, 0.f, 0.f};
    #pragma unroll
    for (int ks2 = 0; ks2 < 2; ++ks2) {
      #pragma unroll
      for (int kt = 0; kt < 4; ++kt) {
        bf16x8 kf = *reinterpret_cast<const bf16x8*>(&Ks[kt * 16 + l15][ks2 * 32 + lg * 8]);
        sa[kt] = mfma16(kf, qf[ks2], sa[kt]);
      }
    }

    // scale + causal mask + online softmax (lane's keys: kt*16 + lg*4 + r)
    float p[16];
    float smax = -INFINITY;
    const bool diag = (kb == qb);
    #pragma unroll
    for (int kt = 0; kt < 4; ++kt)
      #pragma unroll
      for (int r = 0; r < 4; ++r) {
        float s = sa[kt][r] * 0.125f;
        if (diag && (j0 + kt * 16 + lg * 4 + r) > q_abs) s = -INFINITY;
        p[kt * 4 + r] = s;
        smax = fmaxf(smax, s);
      }
    smax = fmaxf(smax, __shfl_xor(smax, 16));
    smax = fmaxf(smax, __shfl_xor(smax, 32));
    const float m_new = fmaxf(m_run, smax);
    const float resc  = __expf(m_run - m_new);
    float psum = 0.f;
    #pragma unroll
    for (int i = 0; i < 16; ++i) {
      float e = __expf(p[i] - m_new);
      p[i] = e;
      psum += e;
    }
    psum += __shfl_xor(psum, 16);
    psum += __shfl_xor(psum, 32);
    l_run = l_run * resc + psum;
    m_run = m_new;
    #pragma unroll
    for (int dt = 0; dt < 4; ++dt) oacc[dt] *= resc;

    // P^T -> LDS (bf16), per-wave region; rows = q (l15), cols = key
    #pragma unroll
    for (int kt = 0; kt < 4; ++kt) {
      bf16x4 pk;
      #pragma unroll
      for (int r = 0; r < 4; ++r) pk[r] = (__bf16)p[kt * 4 + r];
      *reinterpret_cast<bf16x4*>(&Ps[w][l15][kt * 16 + lg * 4]) = pk;
    }

    // O^T += V^T . P^T  (2 key k-steps x 4 d-tiles)
    #pragma unroll
    for (int ks2 = 0; ks2 < 2; ++ks2) {
      bf16x8 pf = *reinterpret_cast<const bf16x8*>(&Ps[w][l15][ks2 * 32 + lg * 8]);
      #pragma unroll
      for (int dt = 0; dt < 4; ++dt) {
        bf16x8 vf = *reinterpret_cast<const bf16x8*>(&Vs[dt * 16 + l15][ks2 * 32 + lg * 8]);
        oacc[dt] = mfma16(vf, pf, oacc[dt]);
      }
    }
    __syncthreads();
  }

  const float inv = 1.f / l_run;
  const int b = bh >> 4, h = bh & 15;
  const size_t rowbase = ((size_t)(b * T + q_abs)) * 1024 + h * 64;
  #pragma unroll
  for (int dt = 0; dt < 4; ++dt) {
    bf16x4 o;
    #pragma unroll
    for (int r = 0; r < 4; ++r) o[r] = (__bf16)(oacc[dt][r] * inv);
    *reinterpret_cast<bf16x4*>(&Ob[rowbase + dt * 16 + lg * 4]) = o;
  }
}

// ---------------------------------------------------------------------------
extern "C" void kernel_launch(void* const* d_in, const int* in_sizes, int n_in,
                              void* d_out, int out_size, void* d_ws, size_t ws_size,
                              hipStream_t stream) {
  const float* x    = (const float*)d_in[0];
  const float* cosT = (const float*)d_in[1];
  const float* sinT = (const float*)d_in[2];
  // d_in[3] = mask (causal, analytic)
  const float* wq   = (const float*)d_in[4];
  const float* wk   = (const float*)d_in[5];
  const float* wv   = (const float*)d_in[6];
  const float* wo   = (const float*)d_in[7];
  float* out = (float*)d_out;

  constexpr size_t XSZ = (size_t)M * D;          // 4,194,304
  constexpr size_t WSZ = (size_t)D * D;          // 1,048,576

  __bf16* xb   = (__bf16*)d_ws;
  __bf16* wqb  = xb  + XSZ;
  __bf16* wkb  = wqb + WSZ;
  __bf16* wvb  = wkb + WSZ;
  __bf16* wob  = wvb + WSZ;
  __bf16* Qh   = wob + WSZ;      // [bh][t][hd]
  __bf16* Kh   = Qh  + XSZ;
  __bf16* Vth  = Kh  + XSZ;      // [bh][hd][t]
  __bf16* attb = Vth + XSZ;      // [M][1024]

  cvt_f2b<<<XSZ / 4 / 256, 256, 0, stream>>>(x,  xb,  (int)XSZ);
  cvt_f2b<<<WSZ / 4 / 256, 256, 0, stream>>>(wq, wqb, (int)WSZ);
  cvt_f2b<<<WSZ / 4 / 256, 256, 0, stream>>>(wk, wkb, (int)WSZ);
  cvt_f2b<<<WSZ / 4 / 256, 256, 0, stream>>>(wv, wvb, (int)WSZ);
  cvt_f2b<<<WSZ / 4 / 256, 256, 0, stream>>>(wo, wob, (int)WSZ);

  dim3 ggrid(D / 128, M / 128);   // (8, 32)
  gemm_bf16<1><<<ggrid, 256, 0, stream>>>(xb, wqb, Qh);
  gemm_bf16<1><<<ggrid, 256, 0, stream>>>(xb, wkb, Kh);
  gemm_bf16<2><<<ggrid, 256, 0, stream>>>(xb, wvb, Vth);

  const int rope_blocks = B * H * T * 8 / 256;   // 2048
  rope_b<<<rope_blocks, 256, 0, stream>>>(Qh, cosT, sinT);
  rope_b<<<rope_blocks, 256, 0, stream>>>(Kh, cosT, sinT);

  dim3 agrid(T / 64, B * H);      // (32, 32)
  attn_mfma<<<agrid, 256, 0, stream>>>(Qh, Kh, Vth, attb);

  gemm_bf16<0><<<ggrid, 256, 0, stream>>>(attb, wob, out);
}